// Round 7
// baseline (4887.131 us; speedup 1.0000x reference)
//
#include <hip/hip_runtime.h>
#include <math.h>

#define S 2048
#define MARGIN 0.7f
#define ITERS 500
#define NBLK 256    // cooperative grid: 1 block/CU on 256 CUs
#define TPB 512     // 8 waves/block, wave-per-row, 8 rows/block
#define NREP 8      // value replicas: 32 pollers/word, 8 lines/block store

typedef unsigned long long u64;

// val layout (per kind): [2 slots][NREP][2048] u64 ; slot stride 1<<14
#define SLOT_STRIDE 16384

// ---------------------------------------------------------------------------
// init: log-marginals, zero accumulators, poison ALL tagged words (replay-safe)
// ---------------------------------------------------------------------------
__global__ __launch_bounds__(256) void init_marg_k(const float* __restrict__ qa,
                                                   const float* __restrict__ ta,
                                                   float* __restrict__ lmu,
                                                   float* __restrict__ lnu,
                                                   float* __restrict__ vt,
                                                   float* __restrict__ dist2,
                                                   u64* __restrict__ valU,
                                                   u64* __restrict__ valV) {
  int i = blockIdx.x * 256 + threadIdx.x;   // 0..2047
  lmu[i] = __logf(qa[i]);
  lnu[i] = __logf(ta[i]);
  vt[i] = 0.f;     // will accumulate y2 (vt init = v0 + y2 = y2 since v0 = 0)
  dist2[i] = 0.f;
  const u64 poison = 0xFFFFFFFF00000000ull;  // hi>>1 never equals any ph
#pragma unroll
  for (int k = 0; k < 16; ++k) {             // 2 slots x 8 reps each kind
    valU[i + (k << 11)] = poison;
    valV[i + (k << 11)] = poison;
  }
}

// vt[j] += sum_d TF[d,j]^2   (8 j-blocks x 8 d-chunks, atomic combine)
__global__ __launch_bounds__(256) void colsumsq_k(const float* __restrict__ TF,
                                                  float* __restrict__ vt) {
  int jb = blockIdx.x & 7, dc = blockIdx.x >> 3;
  int j = jb * 256 + threadIdx.x;
  int d0 = dc * 256;
  float acc = 0.f;
  for (int d = d0; d < d0 + 256; ++d) {
    float v = TF[d * S + j];
    acc = fmaf(v, v, acc);
  }
  atomicAdd(&vt[j], acc);
}

// valV slot0 <- pack(v0=y2, ph=0, changed=1) in all NREP replicas
__global__ __launch_bounds__(256) void pack_v0_k(const float* __restrict__ vt,
                                                 u64* __restrict__ valV) {
  int i = blockIdx.x * 256 + threadIdx.x;
  u64 w = (1ull << 32) | (u64)__float_as_uint(vt[i]);  // hi=(0<<1)|1
#pragma unroll
  for (int r = 0; r < NREP; ++r) valV[(r << 11) + i] = w;
}

// ---------------------------------------------------------------------------
// C[i,j] = alpha * sum_k A[k*S+i] * B[k*S+j]   (128x128 tile, BK=16, 8x8/thread)
// ---------------------------------------------------------------------------
__global__ __launch_bounds__(256) void gemm_tn_k(const float* __restrict__ A,
                                                 const float* __restrict__ B,
                                                 float* __restrict__ C, float alpha) {
  __shared__ float As[16][128];
  __shared__ float Bs[16][128];
  int t = threadIdx.x;
  int i0 = blockIdx.y * 128, j0 = blockIdx.x * 128;
  int tx = t & 15, ty = t >> 4;
  float acc[8][8];
#pragma unroll
  for (int r = 0; r < 8; ++r)
#pragma unroll
    for (int c = 0; c < 8; ++c) acc[r][c] = 0.f;

  int e = t * 4;
  int dd0 = e >> 7, ii = e & 127;
  int dd1 = dd0 + 8;
  for (int k0 = 0; k0 < S; k0 += 16) {
    float4 a0 = *(const float4*)&A[(k0 + dd0) * S + i0 + ii];
    float4 b0 = *(const float4*)&B[(k0 + dd0) * S + j0 + ii];
    float4 a1 = *(const float4*)&A[(k0 + dd1) * S + i0 + ii];
    float4 b1 = *(const float4*)&B[(k0 + dd1) * S + j0 + ii];
    __syncthreads();
    *(float4*)&As[dd0][ii] = a0; *(float4*)&Bs[dd0][ii] = b0;
    *(float4*)&As[dd1][ii] = a1; *(float4*)&Bs[dd1][ii] = b1;
    __syncthreads();
#pragma unroll
    for (int kk = 0; kk < 16; ++kk) {
      float a[8], b[8];
      *(float4*)&a[0] = *(const float4*)&As[kk][ty * 8];
      *(float4*)&a[4] = *(const float4*)&As[kk][ty * 8 + 4];
      *(float4*)&b[0] = *(const float4*)&Bs[kk][tx * 4];
      *(float4*)&b[4] = *(const float4*)&Bs[kk][64 + tx * 4];
#pragma unroll
      for (int r = 0; r < 8; ++r)
#pragma unroll
        for (int c = 0; c < 8; ++c) acc[r][c] = fmaf(a[r], b[c], acc[r][c]);
    }
  }
#pragma unroll
  for (int r = 0; r < 8; ++r) {
    int i = i0 + ty * 8 + r;
    float4 o0 = make_float4(acc[r][0] * alpha, acc[r][1] * alpha, acc[r][2] * alpha, acc[r][3] * alpha);
    float4 o1 = make_float4(acc[r][4] * alpha, acc[r][5] * alpha, acc[r][6] * alpha, acc[r][7] * alpha);
    *(float4*)&C[i * S + j0 + tx * 4] = o0;
    *(float4*)&C[i * S + j0 + 64 + tx * 4] = o1;
  }
}

// ---------------------------------------------------------------------------
// out[j*S+i] = in[i*S+j]  (64x64 LDS tiles)
// ---------------------------------------------------------------------------
__global__ __launch_bounds__(256) void transpose_k(const float* __restrict__ in,
                                                   float* __restrict__ out) {
  __shared__ float tile[64][65];
  int i0 = blockIdx.y * 64, j0 = blockIdx.x * 64;
  int tx = threadIdx.x & 63, ty = threadIdx.x >> 6;  // ty 0..3
#pragma unroll
  for (int r = 0; r < 16; ++r) {
    int row = r * 4 + ty;
    tile[row][tx] = in[(i0 + row) * S + j0 + tx];
  }
  __syncthreads();
#pragma unroll
  for (int r = 0; r < 16; ++r) {
    int row = r * 4 + ty;
    out[(j0 + row) * S + i0 + tx] = tile[tx][row];
  }
}

// ---------------------------------------------------------------------------
// Persistent cooperative Sinkhorn — LDS-resident G + SINGLE-HOP replicated
// dataflow + exact bitwise early exit.
//
// Publish: 8 tagged words (ph<<1|chg)<<32|bits, replicated x8 (one 64B line
// per replica), one wave-0 store instruction. Consumer uses replica bid&7
// -> 32 pollers/word (contention capped; rounds-4/5 lesson). Wave 0 polls
// only the 256 line-sentinels; all 512 threads then read their 4 words ONCE
// with tag verification (covers non-atomic line visibility), deposit as
// conflict-free float4, and OR the changed bits (ballot+LDS). If a consumed
// vector is globally bit-identical to its predecessor, all remaining
// iterations are identities -> uniform, bit-exact break.
// WAR on slots (it&1): overwrite of v_t requires all u_{t+1} reads, which
// requires every block finished reading v_t. Tags strictly increase and are
// poisoned in init -> graph-replay safe.
// ---------------------------------------------------------------------------
#define PADD(P, A) P.x += A.x; P.y += A.y; P.z += A.z; P.w += A.w
#define PMAX(P) fmaxf(fmaxf(P.x, P.y), fmaxf(P.z, P.w))
#define PEXPS(P) (__expf(P.x - m) + __expf(P.y - m) + __expf(P.z - m) + __expf(P.w - m))
#define ALD(p) __hip_atomic_load((p), __ATOMIC_RELAXED, __HIP_MEMORY_SCOPE_AGENT)

// consume phase-ph vector from base (slot+replica resolved); returns global
// changed-OR (uniform across the block and across all blocks)
__device__ __forceinline__ unsigned consume(const u64* __restrict__ base,
                                            unsigned ph,
                                            float* __restrict__ s_pot,
                                            unsigned* __restrict__ s_chgW,
                                            int t, int wv, int lane) {
  if (t < 64) {                       // wave 0: poll 256 line-sentinels
    unsigned got = 0;
    const int L0 = t << 2;
    while (got != 0xFu) {
#pragma unroll
      for (int k = 0; k < 4; ++k)
        if (!(got & (1u << k)))
          if ((unsigned)(ALD(&base[(L0 + k) << 3]) >> 33) == ph)
            got |= 1u << k;
    }
  }
  __syncthreads();
  const int e = t << 2;
  u64 w0 = ALD(&base[e + 0]);
  u64 w1 = ALD(&base[e + 1]);
  u64 w2 = ALD(&base[e + 2]);
  u64 w3 = ALD(&base[e + 3]);
  unsigned ok = 0;
  do {                                 // tag-verify; re-load rare stragglers
    if (!(ok & 1u)) { if ((unsigned)(w0 >> 33) == ph) ok |= 1u; else w0 = ALD(&base[e + 0]); }
    if (!(ok & 2u)) { if ((unsigned)(w1 >> 33) == ph) ok |= 2u; else w1 = ALD(&base[e + 1]); }
    if (!(ok & 4u)) { if ((unsigned)(w2 >> 33) == ph) ok |= 4u; else w2 = ALD(&base[e + 2]); }
    if (!(ok & 8u)) { if ((unsigned)(w3 >> 33) == ph) ok |= 8u; else w3 = ALD(&base[e + 3]); }
  } while (ok != 0xFu);
  unsigned chg = (unsigned)((w0 | w1 | w2 | w3) >> 32) & 1u;
  *(float4*)&s_pot[e] = make_float4(__uint_as_float((unsigned)w0),
                                    __uint_as_float((unsigned)w1),
                                    __uint_as_float((unsigned)w2),
                                    __uint_as_float((unsigned)w3));
  unsigned long long any = __ballot(chg != 0u);
  if (lane == 0) s_chgW[wv] = (any != 0ull) ? 1u : 0u;
  __syncthreads();                     // s_pot staged + all wave flags written
  return s_chgW[0] | s_chgW[1] | s_chgW[2] | s_chgW[3] |
         s_chgW[4] | s_chgW[5] | s_chgW[6] | s_chgW[7];
}

// wave-uniform LSE over 2048 entries of (grow[j] + s_pot[j]); exact row max
__device__ __forceinline__ float lse_row(const float* __restrict__ grow,
                                         const float* __restrict__ s_pot,
                                         int lane) {
  int j0 = lane << 2;
  float4 p0 = *(const float4*)&s_pot[j0];
  float4 p1 = *(const float4*)&s_pot[j0 + 256];
  float4 p2 = *(const float4*)&s_pot[j0 + 512];
  float4 p3 = *(const float4*)&s_pot[j0 + 768];
  float4 p4 = *(const float4*)&s_pot[j0 + 1024];
  float4 p5 = *(const float4*)&s_pot[j0 + 1280];
  float4 p6 = *(const float4*)&s_pot[j0 + 1536];
  float4 p7 = *(const float4*)&s_pot[j0 + 1792];
  float4 a0 = *(const float4*)&grow[j0];
  float4 a1 = *(const float4*)&grow[j0 + 256];
  float4 a2 = *(const float4*)&grow[j0 + 512];
  float4 a3 = *(const float4*)&grow[j0 + 768];
  float4 a4 = *(const float4*)&grow[j0 + 1024];
  float4 a5 = *(const float4*)&grow[j0 + 1280];
  float4 a6 = *(const float4*)&grow[j0 + 1536];
  float4 a7 = *(const float4*)&grow[j0 + 1792];
  PADD(p0, a0); PADD(p1, a1); PADD(p2, a2); PADD(p3, a3);
  PADD(p4, a4); PADD(p5, a5); PADD(p6, a6); PADD(p7, a7);
  float m0 = PMAX(p0), m1 = PMAX(p1), m2 = PMAX(p2), m3 = PMAX(p3);
  float m4 = PMAX(p4), m5 = PMAX(p5), m6 = PMAX(p6), m7 = PMAX(p7);
  m0 = fmaxf(m0, m1); m2 = fmaxf(m2, m3); m4 = fmaxf(m4, m5); m6 = fmaxf(m6, m7);
  float m = fmaxf(fmaxf(m0, m2), fmaxf(m4, m6));
#pragma unroll
  for (int off = 32; off; off >>= 1) m = fmaxf(m, __shfl_xor(m, off));
  float s = PEXPS(p0) + PEXPS(p1) + PEXPS(p2) + PEXPS(p3) +
            PEXPS(p4) + PEXPS(p5) + PEXPS(p6) + PEXPS(p7);
#pragma unroll
  for (int off = 32; off; off >>= 1) s += __shfl_xor(s, off);
  return m + __logf(s);
}

__global__ __launch_bounds__(TPB) void sinkhorn_k(
    const float* __restrict__ Gp, const float* __restrict__ GpT,
    const float* __restrict__ lmu, const float* __restrict__ lnu,
    float* __restrict__ ut, float* __restrict__ vt,
    u64* __restrict__ valU, u64* __restrict__ valV) {
  __shared__ float s_gu[8 * S];    // 64KB: this block's 8 Gp rows
  __shared__ float s_gv[8 * S];    // 64KB: this block's 8 GpT rows
  __shared__ float s_pot[S];       // 8KB : staged potential (single buffer)
  __shared__ float s_res[8];
  __shared__ unsigned s_resC[8];
  __shared__ unsigned s_chgW[8];

  const int t = threadIdx.x;
  const int wv = t >> 6, lane = t & 63;
  const int bid = (int)blockIdx.x;
  const int row = (bid << 3) + wv;
  const int rep = bid & (NREP - 1);          // this block's consume replica

  // one-time stage of this block's G rows into LDS
  {
    const float* gu = Gp + (size_t)row * S;
    const float* gv = GpT + (size_t)row * S;
    float* lgu = s_gu + wv * S;
    float* lgv = s_gv + wv * S;
#pragma unroll
    for (int c = 0; c < 8; ++c) {
      int j = (lane << 2) + (c << 8);
      *(float4*)&lgu[j] = *(const float4*)&gu[j];
      *(float4*)&lgv[j] = *(const float4*)&gv[j];
    }
  }
  const float lmu_r = lmu[row];
  const float lnu_r = lnu[row];
  const float* grow_u = s_gu + wv * S;
  const float* grow_v = s_gv + wv * S;
  float prevU = __uint_as_float(0x7fc00000u);  // NaN: first compare -> changed
  float prevV = prevU;
  float uLast = 0.f, vLast = 0.f;
  __syncthreads();

  for (int it = 0; it < ITERS; ++it) {
    const size_t so = (size_t)(it & 1) * SLOT_STRIDE;
    const unsigned phv = 2u * (unsigned)it;  // tag phase of v_it

    // ---- u-pass: u_t = lmu - LSE(Gp + v_t) ----
    unsigned changed = consume(valV + so + ((size_t)rep << 11), phv,
                               s_pot, s_chgW, t, wv, lane);
    if (changed == 0u) break;   // v_t == v_{t-1} bitwise -> fixed point (exact)
    {
      float nu = lmu_r - lse_row(grow_u, s_pot, lane);
      uLast = nu;
      if (lane == 0) {
        s_res[wv] = nu;
        s_resC[wv] = (__float_as_uint(nu) != __float_as_uint(prevU)) ? 1u : 0u;
        prevU = nu;
      }
    }
    __syncthreads();
    if (t < 64) {  // publish u_t: 8 replicas x 8 rows, one store instruction
      int jj = t & 7;
      u64 w = ((u64)(((phv + 1u) << 1) | s_resC[jj]) << 32) |
              (u64)__float_as_uint(s_res[jj]);
      __hip_atomic_store(&valU[so + ((size_t)(t >> 3) << 11) + (bid << 3) + jj],
                         w, __ATOMIC_RELAXED, __HIP_MEMORY_SCOPE_AGENT);
    }

    // ---- v-pass: v_{t+1} = lnu - LSE(GpT + u_t) ----
    changed = consume(valU + so + ((size_t)rep << 11), phv + 1u,
                      s_pot, s_chgW, t, wv, lane);
    if (changed == 0u) break;   // u_t == u_{t-1} bitwise -> fixed point (exact)
    {
      float nv = lnu_r - lse_row(grow_v, s_pot, lane);
      vLast = nv;
      if (lane == 0) {
        s_res[wv] = nv;
        s_resC[wv] = (__float_as_uint(nv) != __float_as_uint(prevV)) ? 1u : 0u;
        prevV = nv;
      }
    }
    __syncthreads();
    {
      const size_t so2 = (size_t)((it + 1) & 1) * SLOT_STRIDE;
      if (t < 64) {  // publish v_{t+1}
        int jj = t & 7;
        u64 w = ((u64)(((phv + 2u) << 1) | s_resC[jj]) << 32) |
                (u64)__float_as_uint(s_res[jj]);
        __hip_atomic_store(&valV[so2 + ((size_t)(t >> 3) << 11) + (bid << 3) + jj],
                           w, __ATOMIC_RELAXED, __HIP_MEMORY_SCOPE_AGENT);
      }
    }
  }
  // final potentials -> plain arrays for the epilogue kernels
  if (lane == 0) {
    ut[row] = uLast;
    vt[row] = vLast;
  }
}

// ---------------------------------------------------------------------------
// RT[d,i] = sum_j TF[d,j] * exp( GpT[j*S+i] + ut[i] + vt[j] )
// ---------------------------------------------------------------------------
__global__ __launch_bounds__(256) void rt_gemm_k(const float* __restrict__ TF,
                                                 const float* __restrict__ GpT,
                                                 const float* __restrict__ ut,
                                                 const float* __restrict__ vt,
                                                 float* __restrict__ RT) {
  __shared__ float As[16][128];
  __shared__ float Bs[16][128];
  int t = threadIdx.x;
  int d0 = blockIdx.y * 128, i0 = blockIdx.x * 128;
  int tx = t & 15, ty = t >> 4;
  float acc[8][8];
#pragma unroll
  for (int r = 0; r < 8; ++r)
#pragma unroll
    for (int c = 0; c < 8; ++c) acc[r][c] = 0.f;

  int akk = (t * 4) & 15, add0 = t >> 2;
  int eb = t * 4;
  int bkk0 = eb >> 7, bii = eb & 127, bkk1 = bkk0 + 8;
  float4 u4 = *(const float4*)&ut[i0 + bii];

  for (int k0 = 0; k0 < S; k0 += 16) {
    float4 av0 = *(const float4*)&TF[(d0 + add0) * S + k0 + akk];
    float4 av1 = *(const float4*)&TF[(d0 + add0 + 64) * S + k0 + akk];
    float4 g0 = *(const float4*)&GpT[(k0 + bkk0) * S + i0 + bii];
    float4 g1 = *(const float4*)&GpT[(k0 + bkk1) * S + i0 + bii];
    float v0 = vt[k0 + bkk0], v1 = vt[k0 + bkk1];
    __syncthreads();
    As[akk + 0][add0] = av0.x; As[akk + 1][add0] = av0.y;
    As[akk + 2][add0] = av0.z; As[akk + 3][add0] = av0.w;
    As[akk + 0][add0 + 64] = av1.x; As[akk + 1][add0 + 64] = av1.y;
    As[akk + 2][add0 + 64] = av1.z; As[akk + 3][add0 + 64] = av1.w;
    float4 p0 = make_float4(__expf(g0.x + u4.x + v0), __expf(g0.y + u4.y + v0),
                            __expf(g0.z + u4.z + v0), __expf(g0.w + u4.w + v0));
    float4 p1 = make_float4(__expf(g1.x + u4.x + v1), __expf(g1.y + u4.y + v1),
                            __expf(g1.z + u4.z + v1), __expf(g1.w + u4.w + v1));
    *(float4*)&Bs[bkk0][bii] = p0;
    *(float4*)&Bs[bkk1][bii] = p1;
    __syncthreads();
#pragma unroll
    for (int kk = 0; kk < 16; ++kk) {
      float a[8], b[8];
      *(float4*)&a[0] = *(const float4*)&As[kk][ty * 8];
      *(float4*)&a[4] = *(const float4*)&As[kk][ty * 8 + 4];
      *(float4*)&b[0] = *(const float4*)&Bs[kk][tx * 4];
      *(float4*)&b[4] = *(const float4*)&Bs[kk][64 + tx * 4];
#pragma unroll
      for (int r = 0; r < 8; ++r)
#pragma unroll
        for (int c = 0; c < 8; ++c) acc[r][c] = fmaf(a[r], b[c], acc[r][c]);
    }
  }
#pragma unroll
  for (int r = 0; r < 8; ++r) {
    int d = d0 + ty * 8 + r;
    *(float4*)&RT[d * S + i0 + tx * 4] = *(float4*)&acc[r][0];
    *(float4*)&RT[d * S + i0 + 64 + tx * 4] = *(float4*)&acc[r][4];
  }
}

// dist2[i] += sum_{d in chunk} (qa[i]*QF[d,i] - RT[d,i])^2
__global__ __launch_bounds__(256) void dist2_partial_k(const float* __restrict__ QF,
                                                       const float* __restrict__ RT,
                                                       const float* __restrict__ qa,
                                                       float* __restrict__ dist2) {
  int ib = blockIdx.x & 7, dc = blockIdx.x >> 3;
  int i = ib * 256 + threadIdx.x;
  float qai = qa[i];
  float acc = 0.f;
  int d0 = dc * 256;
  for (int d = d0; d < d0 + 256; ++d) {
    float q = QF[d * S + i];
    float r = RT[d * S + i];
    float x = fmaf(qai, q, -r);
    acc = fmaf(x, x, acc);
  }
  atomicAdd(&dist2[i], acc);
}

__global__ __launch_bounds__(256) void loss_final_k(const float* __restrict__ dist2,
                                                    const float* __restrict__ label,
                                                    float* __restrict__ out) {
  int t = threadIdx.x;
  float acc = 0.f;
#pragma unroll
  for (int k = 0; k < 8; ++k) {
    int i = t + k * 256;
    float d2 = dist2[i];
    float dist = sqrtf(d2);
    float lab = label[i];
    float neg = fmaxf(MARGIN - dist, 0.f);
    acc += 0.5f * lab * d2 + 0.5f * (1.f - lab) * neg * neg;
  }
#pragma unroll
  for (int off = 32; off; off >>= 1) acc += __shfl_xor(acc, off);
  __shared__ float wsum[4];
  int wave = t >> 6, lane = t & 63;
  if (lane == 0) wsum[wave] = acc;
  __syncthreads();
  if (t == 0) out[0] = wsum[0] + wsum[1] + wsum[2] + wsum[3];
}

// ---------------------------------------------------------------------------
extern "C" void kernel_launch(void* const* d_in, const int* in_sizes, int n_in,
                              void* d_out, int out_size, void* d_ws, size_t ws_size,
                              hipStream_t stream) {
  const float* QF  = (const float*)d_in[0];  // [D, m] d-major
  const float* qa  = (const float*)d_in[1];  // [m]
  const float* TF  = (const float*)d_in[2];  // [D, n] d-major
  const float* ta  = (const float*)d_in[3];  // [n]
  const float* lab = (const float*)d_in[4];  // [m]
  float* out = (float*)d_out;

  float* ws = (float*)d_ws;
  float* Gp    = ws;                  // S*S : G' = -2 X^T Y  (reused as RT later)
  float* GpT   = Gp + S * S;          // S*S : G'^T
  float* ut    = GpT + S * S;         // S
  float* vt    = ut + S;              // S
  float* lmu   = vt + S;              // S
  float* lnu   = lmu + S;             // S
  float* dist2 = lnu + S;             // S
  u64* valU = (u64*)(dist2 + S);      // [2][NREP][2048] u64 (256KB)
  u64* valV = valU + 2 * SLOT_STRIDE; // [2][NREP][2048] u64 (256KB)
  // total: 2*S*S + 5*S floats + 512KB sync state ~= 34.1 MB

  init_marg_k<<<8, 256, 0, stream>>>(qa, ta, lmu, lnu, vt, dist2, valU, valV);
  colsumsq_k<<<64, 256, 0, stream>>>(TF, vt);   // vt = y2 (== v0 + y2)
  pack_v0_k<<<8, 256, 0, stream>>>(vt, valV);
  gemm_tn_k<<<dim3(16, 16), 256, 0, stream>>>(QF, TF, Gp, -2.0f);
  transpose_k<<<dim3(32, 32), 256, 0, stream>>>(Gp, GpT);

  // whole Sinkhorn loop in one persistent cooperative kernel (static 136KB LDS)
  {
    const float* cGp = Gp; const float* cGpT = GpT;
    const float* clmu = lmu; const float* clnu = lnu;
    float* cut = ut; float* cvt = vt;
    u64* cvalU = valU; u64* cvalV = valV;
    void* kargs[] = {&cGp, &cGpT, &clmu, &clnu, &cut, &cvt, &cvalU, &cvalV};
    hipLaunchCooperativeKernel((const void*)sinkhorn_k, dim3(NBLK), dim3(TPB),
                               kargs, 0, stream);
  }

  // RT = P @ tf computed transposed: RT[d,i]; aliases Gp (G' dead after loop)
  rt_gemm_k<<<dim3(16, 16), 256, 0, stream>>>(TF, GpT, ut, vt, Gp);
  dist2_partial_k<<<64, 256, 0, stream>>>(QF, Gp, qa, dist2);
  loss_final_k<<<1, 256, 0, stream>>>(dist2, lab, out);
}

// Round 8
// 4464.906 us; speedup vs baseline: 1.0946x; 1.0946x over previous
//
#include <hip/hip_runtime.h>
#include <math.h>

#define S 2048
#define MARGIN 0.7f
#define ITERS 500

// ---------------------------------------------------------------------------
// init: log-marginals, zero accumulators
// ---------------------------------------------------------------------------
__global__ __launch_bounds__(256) void init_marg_k(const float* __restrict__ qa,
                                                   const float* __restrict__ ta,
                                                   float* __restrict__ lmu,
                                                   float* __restrict__ lnu,
                                                   float* __restrict__ vt,
                                                   float* __restrict__ dist2) {
  int i = blockIdx.x * 256 + threadIdx.x;
  lmu[i] = __logf(qa[i]);
  lnu[i] = __logf(ta[i]);
  vt[i] = 0.f;     // will accumulate y2 (vt init = v0 + y2 = y2 since v0 = 0)
  dist2[i] = 0.f;
}

// vt[j] += sum_d TF[d,j]^2   (8 j-blocks x 8 d-chunks, atomic combine)
__global__ __launch_bounds__(256) void colsumsq_k(const float* __restrict__ TF,
                                                  float* __restrict__ vt) {
  int jb = blockIdx.x & 7, dc = blockIdx.x >> 3;
  int j = jb * 256 + threadIdx.x;
  int d0 = dc * 256;
  float acc = 0.f;
  for (int d = d0; d < d0 + 256; ++d) {
    float v = TF[d * S + j];
    acc = fmaf(v, v, acc);
  }
  atomicAdd(&vt[j], acc);
}

// ---------------------------------------------------------------------------
// C[i,j] = alpha * sum_k A[k*S+i] * B[k*S+j]   (128x128 tile, BK=16, 8x8/thread)
// ---------------------------------------------------------------------------
__global__ __launch_bounds__(256) void gemm_tn_k(const float* __restrict__ A,
                                                 const float* __restrict__ B,
                                                 float* __restrict__ C, float alpha) {
  __shared__ float As[16][128];
  __shared__ float Bs[16][128];
  int t = threadIdx.x;
  int i0 = blockIdx.y * 128, j0 = blockIdx.x * 128;
  int tx = t & 15, ty = t >> 4;
  float acc[8][8];
#pragma unroll
  for (int r = 0; r < 8; ++r)
#pragma unroll
    for (int c = 0; c < 8; ++c) acc[r][c] = 0.f;

  int e = t * 4;
  int dd0 = e >> 7, ii = e & 127;
  int dd1 = dd0 + 8;
  for (int k0 = 0; k0 < S; k0 += 16) {
    float4 a0 = *(const float4*)&A[(k0 + dd0) * S + i0 + ii];
    float4 b0 = *(const float4*)&B[(k0 + dd0) * S + j0 + ii];
    float4 a1 = *(const float4*)&A[(k0 + dd1) * S + i0 + ii];
    float4 b1 = *(const float4*)&B[(k0 + dd1) * S + j0 + ii];
    __syncthreads();
    *(float4*)&As[dd0][ii] = a0; *(float4*)&Bs[dd0][ii] = b0;
    *(float4*)&As[dd1][ii] = a1; *(float4*)&Bs[dd1][ii] = b1;
    __syncthreads();
#pragma unroll
    for (int kk = 0; kk < 16; ++kk) {
      float a[8], b[8];
      *(float4*)&a[0] = *(const float4*)&As[kk][ty * 8];
      *(float4*)&a[4] = *(const float4*)&As[kk][ty * 8 + 4];
      *(float4*)&b[0] = *(const float4*)&Bs[kk][tx * 4];
      *(float4*)&b[4] = *(const float4*)&Bs[kk][64 + tx * 4];
#pragma unroll
      for (int r = 0; r < 8; ++r)
#pragma unroll
        for (int c = 0; c < 8; ++c) acc[r][c] = fmaf(a[r], b[c], acc[r][c]);
    }
  }
#pragma unroll
  for (int r = 0; r < 8; ++r) {
    int i = i0 + ty * 8 + r;
    float4 o0 = make_float4(acc[r][0] * alpha, acc[r][1] * alpha, acc[r][2] * alpha, acc[r][3] * alpha);
    float4 o1 = make_float4(acc[r][4] * alpha, acc[r][5] * alpha, acc[r][6] * alpha, acc[r][7] * alpha);
    *(float4*)&C[i * S + j0 + tx * 4] = o0;
    *(float4*)&C[i * S + j0 + 64 + tx * 4] = o1;
  }
}

// ---------------------------------------------------------------------------
// out[j*S+i] = in[i*S+j]  (64x64 LDS tiles)
// ---------------------------------------------------------------------------
__global__ __launch_bounds__(256) void transpose_k(const float* __restrict__ in,
                                                   float* __restrict__ out) {
  __shared__ float tile[64][65];
  int i0 = blockIdx.y * 64, j0 = blockIdx.x * 64;
  int tx = threadIdx.x & 63, ty = threadIdx.x >> 6;  // ty 0..3
#pragma unroll
  for (int r = 0; r < 16; ++r) {
    int row = r * 4 + ty;
    tile[row][tx] = in[(i0 + row) * S + j0 + tx];
  }
  __syncthreads();
#pragma unroll
  for (int r = 0; r < 16; ++r) {
    int row = r * 4 + ty;
    out[(j0 + row) * S + i0 + tx] = tile[tx][row];
  }
}

// ---------------------------------------------------------------------------
// lse8_k: 4 rows per block, wave-per-row, pot staged once in LDS.
//
// outPot[row] = logMarg[row] - LSE_j( G[row*S+j] + inPot[j] )
// grid 512 x block 256 (4 waves). Round 0's one-block-per-row kernel re-read
// the 8KB pot vector 2048x (16.8MB/pass, equal to the G read itself: 33.6MB
// total at 8.2 TB/s = 4.1us). Staging pot once per block cuts per-pass
// traffic to 16.8 + 4 = 20.8MB. Arithmetic identical to the persistent
// lse_row (rounds 3/5/6/7, absmax 0.0): pot via LDS float4, G via global
// float4, same PADD/PMAX tree, same shfl_xor reductions -> bit-identical.
// Graph-serialized launches provide the inter-pass barrier for free.
// ---------------------------------------------------------------------------
#define PADD(P, A) P.x += A.x; P.y += A.y; P.z += A.z; P.w += A.w
#define PMAX(P) fmaxf(fmaxf(P.x, P.y), fmaxf(P.z, P.w))
#define PEXPS(P) (__expf(P.x - m) + __expf(P.y - m) + __expf(P.z - m) + __expf(P.w - m))

__global__ __launch_bounds__(256) void lse8_k(const float* __restrict__ G,
                                              const float* __restrict__ inPot,
                                              const float* __restrict__ logMarg,
                                              float* __restrict__ outPot) {
  __shared__ float s_pot[S];
  const int t = threadIdx.x;
  const int wv = t >> 6, lane = t & 63;
  const int row = (int)blockIdx.x * 4 + wv;

  // stage pot: 256 threads x 8 floats = 8KB, coalesced, conflict-free
  {
    int e = t << 3;
    *(float4*)&s_pot[e] = *(const float4*)&inPot[e];
    *(float4*)&s_pot[e + 4] = *(const float4*)&inPot[e + 4];
  }
  __syncthreads();

  const float* g = G + (size_t)row * S;
  const int j0 = lane << 2;
  float4 p0 = *(const float4*)&s_pot[j0];
  float4 p1 = *(const float4*)&s_pot[j0 + 256];
  float4 p2 = *(const float4*)&s_pot[j0 + 512];
  float4 p3 = *(const float4*)&s_pot[j0 + 768];
  float4 p4 = *(const float4*)&s_pot[j0 + 1024];
  float4 p5 = *(const float4*)&s_pot[j0 + 1280];
  float4 p6 = *(const float4*)&s_pot[j0 + 1536];
  float4 p7 = *(const float4*)&s_pot[j0 + 1792];
  float4 a0 = *(const float4*)&g[j0];
  float4 a1 = *(const float4*)&g[j0 + 256];
  float4 a2 = *(const float4*)&g[j0 + 512];
  float4 a3 = *(const float4*)&g[j0 + 768];
  float4 a4 = *(const float4*)&g[j0 + 1024];
  float4 a5 = *(const float4*)&g[j0 + 1280];
  float4 a6 = *(const float4*)&g[j0 + 1536];
  float4 a7 = *(const float4*)&g[j0 + 1792];
  PADD(p0, a0); PADD(p1, a1); PADD(p2, a2); PADD(p3, a3);
  PADD(p4, a4); PADD(p5, a5); PADD(p6, a6); PADD(p7, a7);
  float m0 = PMAX(p0), m1 = PMAX(p1), m2 = PMAX(p2), m3 = PMAX(p3);
  float m4 = PMAX(p4), m5 = PMAX(p5), m6 = PMAX(p6), m7 = PMAX(p7);
  m0 = fmaxf(m0, m1); m2 = fmaxf(m2, m3); m4 = fmaxf(m4, m5); m6 = fmaxf(m6, m7);
  float m = fmaxf(fmaxf(m0, m2), fmaxf(m4, m6));
#pragma unroll
  for (int off = 32; off; off >>= 1) m = fmaxf(m, __shfl_xor(m, off));
  float s = PEXPS(p0) + PEXPS(p1) + PEXPS(p2) + PEXPS(p3) +
            PEXPS(p4) + PEXPS(p5) + PEXPS(p6) + PEXPS(p7);
#pragma unroll
  for (int off = 32; off; off >>= 1) s += __shfl_xor(s, off);
  if (lane == 0) outPot[row] = logMarg[row] - (m + __logf(s));
}

// ---------------------------------------------------------------------------
// RT[d,i] = sum_j TF[d,j] * exp( GpT[j*S+i] + ut[i] + vt[j] )
// (C = A * P^T with P^T generated on the fly into LDS; 128x128 tile, BK=16)
// ---------------------------------------------------------------------------
__global__ __launch_bounds__(256) void rt_gemm_k(const float* __restrict__ TF,
                                                 const float* __restrict__ GpT,
                                                 const float* __restrict__ ut,
                                                 const float* __restrict__ vt,
                                                 float* __restrict__ RT) {
  __shared__ float As[16][128];
  __shared__ float Bs[16][128];
  int t = threadIdx.x;
  int d0 = blockIdx.y * 128, i0 = blockIdx.x * 128;
  int tx = t & 15, ty = t >> 4;
  float acc[8][8];
#pragma unroll
  for (int r = 0; r < 8; ++r)
#pragma unroll
    for (int c = 0; c < 8; ++c) acc[r][c] = 0.f;

  int akk = (t * 4) & 15, add0 = t >> 2;
  int eb = t * 4;
  int bkk0 = eb >> 7, bii = eb & 127, bkk1 = bkk0 + 8;
  float4 u4 = *(const float4*)&ut[i0 + bii];

  for (int k0 = 0; k0 < S; k0 += 16) {
    float4 av0 = *(const float4*)&TF[(d0 + add0) * S + k0 + akk];
    float4 av1 = *(const float4*)&TF[(d0 + add0 + 64) * S + k0 + akk];
    float4 g0 = *(const float4*)&GpT[(k0 + bkk0) * S + i0 + bii];
    float4 g1 = *(const float4*)&GpT[(k0 + bkk1) * S + i0 + bii];
    float v0 = vt[k0 + bkk0], v1 = vt[k0 + bkk1];
    __syncthreads();
    As[akk + 0][add0] = av0.x; As[akk + 1][add0] = av0.y;
    As[akk + 2][add0] = av0.z; As[akk + 3][add0] = av0.w;
    As[akk + 0][add0 + 64] = av1.x; As[akk + 1][add0 + 64] = av1.y;
    As[akk + 2][add0 + 64] = av1.z; As[akk + 3][add0 + 64] = av1.w;
    float4 p0 = make_float4(__expf(g0.x + u4.x + v0), __expf(g0.y + u4.y + v0),
                            __expf(g0.z + u4.z + v0), __expf(g0.w + u4.w + v0));
    float4 p1 = make_float4(__expf(g1.x + u4.x + v1), __expf(g1.y + u4.y + v1),
                            __expf(g1.z + u4.z + v1), __expf(g1.w + u4.w + v1));
    *(float4*)&Bs[bkk0][bii] = p0;
    *(float4*)&Bs[bkk1][bii] = p1;
    __syncthreads();
#pragma unroll
    for (int kk = 0; kk < 16; ++kk) {
      float a[8], b[8];
      *(float4*)&a[0] = *(const float4*)&As[kk][ty * 8];
      *(float4*)&a[4] = *(const float4*)&As[kk][ty * 8 + 4];
      *(float4*)&b[0] = *(const float4*)&Bs[kk][tx * 4];
      *(float4*)&b[4] = *(const float4*)&Bs[kk][64 + tx * 4];
#pragma unroll
      for (int r = 0; r < 8; ++r)
#pragma unroll
        for (int c = 0; c < 8; ++c) acc[r][c] = fmaf(a[r], b[c], acc[r][c]);
    }
  }
#pragma unroll
  for (int r = 0; r < 8; ++r) {
    int d = d0 + ty * 8 + r;
    *(float4*)&RT[d * S + i0 + tx * 4] = *(float4*)&acc[r][0];
    *(float4*)&RT[d * S + i0 + 64 + tx * 4] = *(float4*)&acc[r][4];
  }
}

// dist2[i] += sum_{d in chunk} (qa[i]*QF[d,i] - RT[d,i])^2
__global__ __launch_bounds__(256) void dist2_partial_k(const float* __restrict__ QF,
                                                       const float* __restrict__ RT,
                                                       const float* __restrict__ qa,
                                                       float* __restrict__ dist2) {
  int ib = blockIdx.x & 7, dc = blockIdx.x >> 3;
  int i = ib * 256 + threadIdx.x;
  float qai = qa[i];
  float acc = 0.f;
  int d0 = dc * 256;
  for (int d = d0; d < d0 + 256; ++d) {
    float q = QF[d * S + i];
    float r = RT[d * S + i];
    float x = fmaf(qai, q, -r);
    acc = fmaf(x, x, acc);
  }
  atomicAdd(&dist2[i], acc);
}

__global__ __launch_bounds__(256) void loss_final_k(const float* __restrict__ dist2,
                                                    const float* __restrict__ label,
                                                    float* __restrict__ out) {
  int t = threadIdx.x;
  float acc = 0.f;
#pragma unroll
  for (int k = 0; k < 8; ++k) {
    int i = t + k * 256;
    float d2 = dist2[i];
    float dist = sqrtf(d2);
    float lab = label[i];
    float neg = fmaxf(MARGIN - dist, 0.f);
    acc += 0.5f * lab * d2 + 0.5f * (1.f - lab) * neg * neg;
  }
#pragma unroll
  for (int off = 32; off; off >>= 1) acc += __shfl_xor(acc, off);
  __shared__ float wsum[4];
  int wave = t >> 6, lane = t & 63;
  if (lane == 0) wsum[wave] = acc;
  __syncthreads();
  if (t == 0) out[0] = wsum[0] + wsum[1] + wsum[2] + wsum[3];
}

// ---------------------------------------------------------------------------
extern "C" void kernel_launch(void* const* d_in, const int* in_sizes, int n_in,
                              void* d_out, int out_size, void* d_ws, size_t ws_size,
                              hipStream_t stream) {
  const float* QF  = (const float*)d_in[0];  // [D, m] d-major
  const float* qa  = (const float*)d_in[1];  // [m]
  const float* TF  = (const float*)d_in[2];  // [D, n] d-major
  const float* ta  = (const float*)d_in[3];  // [n]
  const float* lab = (const float*)d_in[4];  // [m]
  float* out = (float*)d_out;

  float* ws = (float*)d_ws;
  float* Gp    = ws;                  // S*S : G' = -2 X^T Y  (reused as RT later)
  float* GpT   = Gp + S * S;          // S*S : G'^T
  float* ut    = GpT + S * S;         // S
  float* vt    = ut + S;              // S
  float* lmu   = vt + S;              // S
  float* lnu   = lmu + S;             // S
  float* dist2 = lnu + S;             // S
  // total: 2*S*S + 5*S floats ~= 33.6 MB

  init_marg_k<<<8, 256, 0, stream>>>(qa, ta, lmu, lnu, vt, dist2);
  colsumsq_k<<<64, 256, 0, stream>>>(TF, vt);  // vt = y2 (== v0 + y2)
  gemm_tn_k<<<dim3(16, 16), 256, 0, stream>>>(QF, TF, Gp, -2.0f);
  transpose_k<<<dim3(32, 32), 256, 0, stream>>>(Gp, GpT);

  for (int it = 0; it < ITERS; ++it) {
    lse8_k<<<512, 256, 0, stream>>>(Gp, vt, lmu, ut);   // row pass -> ut
    lse8_k<<<512, 256, 0, stream>>>(GpT, ut, lnu, vt);  // col pass -> vt
  }

  // RT = P @ tf computed transposed: RT[d,i]; aliases Gp (G' dead after loop)
  rt_gemm_k<<<dim3(16, 16), 256, 0, stream>>>(TF, GpT, ut, vt, Gp);
  dist2_partial_k<<<64, 256, 0, stream>>>(QF, Gp, qa, dist2);
  loss_final_k<<<1, 256, 0, stream>>>(dist2, lab, out);
}